// Round 14
// baseline (422.771 us; speedup 1.0000x reference)
//
#include <hip/hip_runtime.h>
#include <cstdint>

typedef float f4 __attribute__((ext_vector_type(4)));
typedef float f2 __attribute__((ext_vector_type(2)));
typedef short bfv8 __attribute__((ext_vector_type(8)));   // 8 bf16 = 4 VGPR

__device__ inline f4 f4_zero(){ f4 v = {0.f,0.f,0.f,0.f}; return v; }
__device__ inline f2 f2_zero(){ f2 v = {0.f,0.f}; return v; }

// bf16 helpers: RNE pack, exact unpack
__device__ inline uint32_t f2bf(float f){
    uint32_t u = __float_as_uint(f);
    return (u + 0x7fffu + ((u >> 16) & 1u)) >> 16;
}
__device__ inline uint32_t pack_bf2(float a, float b){
    return f2bf(a) | (f2bf(b) << 16);
}
__device__ inline f2 bf2_unpack(uint32_t v){
    f2 r;
    r[0] = __uint_as_float(v << 16);
    r[1] = __uint_as_float(v & 0xffff0000u);
    return r;
}

#define PB 256  // blocks for hist/scatter. NOTE (R12 lesson): PB IS the grid size
                // for the edge-stream kernels — PB=64 left 3/4 of CUs idle and
                // regressed 38us. Keep 256.

// ---------- inline int64-vs-int32 detection (replaces k_detect launch) ----------
// Checks high words of first 2048 index pairs; all zero => int64. Each block
// redundantly computes the same deterministic answer (16KB read, L2-hot).
__device__ inline bool detect_is64(const uint32_t* p, int* sflag){
    int t = threadIdx.x;
    if (t == 0) *sflag = 0;
    __syncthreads();
    int local = 0;
    for (int i = t; i < 2048; i += blockDim.x)
        if (p[2*i + 1] != 0u) local = 1;
    if (local) atomicOr(sflag, 1);
    __syncthreads();
    return *sflag == 0;
}

// ---------- fp32 -> packed bf16 conversion ----------
__global__ __launch_bounds__(256) void k_tobf16(const f4* __restrict__ in,
                                                uint2* __restrict__ out, int n4){
    int i = blockIdx.x * 256 + threadIdx.x;
    if (i >= n4) return;
    f4 v = in[i];
    uint2 o;
    o.x = pack_bf2(v[0], v[1]);
    o.y = pack_bf2(v[2], v[3]);
    out[i] = o;
}

// ---------- per-block coarse histogram (bucket = dst>>7) ----------
__global__ __launch_bounds__(1024) void k_hist(const void* __restrict__ eidx, int E, int NB,
                                               int* __restrict__ blkhist){
    __shared__ int lh[1024];
    __shared__ int dflag;
    bool is64 = detect_is64((const uint32_t*)eidx, &dflag);
    int t = threadIdx.x, blk = blockIdx.x;
    for (int i = t; i < NB; i += 1024) lh[i] = 0;
    __syncthreads();
    int R = (E + PB - 1) / PB;
    int s = blk * R, e_end = s + R < E ? s + R : E;
    const uint32_t* p32 = (const uint32_t*)eidx;
    const int*      pi  = (const int*)eidx;
    for (int e = s + t; e < e_end; e += 1024){
        int d = is64 ? (int)p32[2*(size_t)(E + e)] : pi[(size_t)E + e];
        atomicAdd(&lh[d >> 7], 1);
    }
    __syncthreads();
    for (int i = t; i < NB; i += 1024)
        blkhist[(size_t)i * PB + blk] = lh[i];      // block-private slot, no atomic
}

// ---------- fused: bucket totals + exclusive scan + per-(bucket,block) offsets ----
// One block, 1024 threads. blkhist/offs are [NB][PB] rows, int4 loads.
__global__ __launch_bounds__(1024) void k_offsets(const int* __restrict__ blkhist,
                                                  int NB,
                                                  int* __restrict__ coff,
                                                  int* __restrict__ offs){
    __shared__ int tot_s[1024];
    __shared__ int excl_s[1024];
    __shared__ int ws[16];
    int t = threadIdx.x, lane = t & 63, w = t >> 6;
    // phase 1: per-bucket totals (thread t owns bucket t)
    int v = 0;
    if (t < NB){
        const int4* row = (const int4*)(blkhist + (size_t)t * PB);
        #pragma unroll 8
        for (int i = 0; i < PB/4; ++i){
            int4 q = row[i];
            v += q.x + q.y + q.z + q.w;
        }
    }
    tot_s[t] = v;
    __syncthreads();
    // phase 2: exclusive scan over 1024 entries (zeros beyond NB)
    int x = tot_s[t];
    int vv = x;
    #pragma unroll
    for (int off = 1; off < 64; off <<= 1){
        int u = __shfl_up(x, off, 64);
        if (lane >= off) x += u;
    }
    if (lane == 63) ws[w] = x;
    __syncthreads();
    if (w == 0 && lane < 16){
        int y = ws[lane];
        #pragma unroll
        for (int off = 1; off < 16; off <<= 1){
            int u = __shfl_up(y, off, 64);
            if (lane >= off) y += u;
        }
        ws[lane] = y;
    }
    __syncthreads();
    int incl = x + (w ? ws[w - 1] : 0);
    int excl = incl - vv;
    excl_s[t] = excl;
    if (t < NB)      coff[t] = excl;
    if (t == NB - 1) coff[NB] = incl;    // == E
    __syncthreads();
    // phase 3: running prefix within each bucket row
    if (t < NB){
        const int4* row  = (const int4*)(blkhist + (size_t)t * PB);
        int4*       orow = (int4*)(offs + (size_t)t * PB);
        int run = excl_s[t];
        #pragma unroll 8
        for (int i = 0; i < PB/4; ++i){
            int4 q = row[i];
            int4 o;
            o.x = run; run += q.x;
            o.y = run; run += q.y;
            o.z = run; run += q.z;
            o.w = run; run += q.w;
            orow[i] = o;
        }
    }
}

// ---------- scatter edges into coarse buckets (packed (dst&127)<<17 | src) ----------
__global__ __launch_bounds__(1024) void k_scatter(const void* __restrict__ eidx, int E, int NB,
                                                  const int* __restrict__ offs,
                                                  uint32_t* __restrict__ bucketed){
    __shared__ int cur[1024];
    __shared__ int dflag;
    bool is64 = detect_is64((const uint32_t*)eidx, &dflag);
    int t = threadIdx.x, blk = blockIdx.x;
    for (int i = t; i < NB; i += 1024) cur[i] = offs[(size_t)i * PB + blk];
    __syncthreads();
    int R = (E + PB - 1) / PB;
    int s = blk * R, e_end = s + R < E ? s + R : E;
    const uint32_t* p32 = (const uint32_t*)eidx;
    const int*      pi  = (const int*)eidx;
    for (int e = s + t; e < e_end; e += 1024){
        int sv, dv;
        if (is64){ sv = (int)p32[2*(size_t)e]; dv = (int)p32[2*(size_t)(E + e)]; }
        else     { sv = pi[e];                 dv = pi[(size_t)E + e]; }
        int b = dv >> 7;
        int pos = atomicAdd(&cur[b], 1);      // LDS atomic; global range block-private
        bucketed[pos] = ((uint32_t)(dv & 127) << 17) | (uint32_t)sv;
    }
}

// ---------- per-bucket counting sort -> full dst-sorted CSR ----------
__global__ __launch_bounds__(1024) void k_bucketsort(const uint32_t* __restrict__ bucketed,
                                                     const int* __restrict__ coff,
                                                     int* __restrict__ esrc,
                                                     int* __restrict__ rowptr,
                                                     int N, int E, int NB){
    __shared__ int hist[128], cur[128], wtot[2];
    int b = blockIdx.x, t = threadIdx.x;
    if (t < 128) hist[t] = 0;
    __syncthreads();
    int s = coff[b], e_end = coff[b + 1];
    for (int i = s + t; i < e_end; i += 1024)
        atomicAdd(&hist[bucketed[i] >> 17], 1);
    __syncthreads();
    int x = 0, v = 0;
    if (t < 128){
        int lane = t & 63;
        v = hist[t]; x = v;
        #pragma unroll
        for (int off = 1; off < 64; off <<= 1){
            int u = __shfl_up(x, off, 64);
            if (lane >= off) x += u;
        }
        if (lane == 63) wtot[t >> 6] = x;
    }
    __syncthreads();
    if (t < 128){
        int w = t >> 6;
        int excl = x - v + (w ? wtot[0] : 0);     // exclusive within bucket
        int abs0 = s + excl;
        cur[t] = abs0;
        int node = b * 128 + t;
        if (node < N) rowptr[node] = abs0;
    }
    if (b == NB - 1 && t == 0) rowptr[N] = E;
    __syncthreads();
    for (int i = s + t; i < e_end; i += 1024){
        uint32_t val = bucketed[i];
        int r = (int)(val >> 17);
        int pos = atomicAdd(&cur[r], 1);
        esrc[pos] = (int)(val & 0x1FFFFu);
    }
}

// ---------- mean aggregation over bf16 features: one wave per dst node ----------
// 2 edges per step: lanes 0-31 even edge, 32-63 odd edge; each lane gathers 8B
// (4 bf16) via dwordx2. Cascade unroll 16/8/2 so mean-deg-16 rows hit the wide
// path: up to 8 dwordx2 loads in flight per half-wave (16/wave, 2x R11 depth —
// targets the latency component of the L2-miss path). Cross-half shfl_xor(32)
// reduce; lanes 0-31 store 8B.
__global__ __launch_bounds__(256) void k_aggregate(const uint32_t* __restrict__ featb,
                                                   const int* __restrict__ rowptr,
                                                   const int* __restrict__ esrc,
                                                   uint32_t* __restrict__ aggb, int N){
    int node = blockIdx.x * 4 + (threadIdx.x >> 6);
    if (node >= N) return;
    int lane = threadIdx.x & 63;
    int half = lane >> 5;          // which edge of the pair
    int l8   = lane & 31;          // 8-byte chunk within row
    int b = rowptr[node], e = rowptr[node + 1];
    f2 lo0=f2_zero(),lo1=f2_zero(),lo2=f2_zero(),lo3=f2_zero();
    f2 lo4=f2_zero(),lo5=f2_zero(),lo6=f2_zero(),lo7=f2_zero();
    f2 hi0=f2_zero(),hi1=f2_zero(),hi2=f2_zero(),hi3=f2_zero();
    f2 hi4=f2_zero(),hi5=f2_zero(),hi6=f2_zero(),hi7=f2_zero();
    for (int base = b; base < e; base += 64){
        int m = e - base; if (m > 64) m = 64;
        int idx = (lane < m) ? esrc[base + lane] : 0;   // vector load, 256B/wave
        int j = 0;
        for (; j + 16 <= m; j += 16){
            int s0 = __shfl(idx, j      + half, 64);
            int s1 = __shfl(idx, j + 2  + half, 64);
            int s2 = __shfl(idx, j + 4  + half, 64);
            int s3 = __shfl(idx, j + 6  + half, 64);
            int s4 = __shfl(idx, j + 8  + half, 64);
            int s5 = __shfl(idx, j + 10 + half, 64);
            int s6 = __shfl(idx, j + 12 + half, 64);
            int s7 = __shfl(idx, j + 14 + half, 64);
            uint2 g0 = *(const uint2*)(featb + (size_t)s0 * 64 + l8 * 2);
            uint2 g1 = *(const uint2*)(featb + (size_t)s1 * 64 + l8 * 2);
            uint2 g2 = *(const uint2*)(featb + (size_t)s2 * 64 + l8 * 2);
            uint2 g3 = *(const uint2*)(featb + (size_t)s3 * 64 + l8 * 2);
            uint2 g4 = *(const uint2*)(featb + (size_t)s4 * 64 + l8 * 2);
            uint2 g5 = *(const uint2*)(featb + (size_t)s5 * 64 + l8 * 2);
            uint2 g6 = *(const uint2*)(featb + (size_t)s6 * 64 + l8 * 2);
            uint2 g7 = *(const uint2*)(featb + (size_t)s7 * 64 + l8 * 2);
            lo0 += bf2_unpack(g0.x); hi0 += bf2_unpack(g0.y);
            lo1 += bf2_unpack(g1.x); hi1 += bf2_unpack(g1.y);
            lo2 += bf2_unpack(g2.x); hi2 += bf2_unpack(g2.y);
            lo3 += bf2_unpack(g3.x); hi3 += bf2_unpack(g3.y);
            lo4 += bf2_unpack(g4.x); hi4 += bf2_unpack(g4.y);
            lo5 += bf2_unpack(g5.x); hi5 += bf2_unpack(g5.y);
            lo6 += bf2_unpack(g6.x); hi6 += bf2_unpack(g6.y);
            lo7 += bf2_unpack(g7.x); hi7 += bf2_unpack(g7.y);
        }
        if (j + 8 <= m){
            int s0 = __shfl(idx, j     + half, 64);
            int s1 = __shfl(idx, j + 2 + half, 64);
            int s2 = __shfl(idx, j + 4 + half, 64);
            int s3 = __shfl(idx, j + 6 + half, 64);
            uint2 g0 = *(const uint2*)(featb + (size_t)s0 * 64 + l8 * 2);
            uint2 g1 = *(const uint2*)(featb + (size_t)s1 * 64 + l8 * 2);
            uint2 g2 = *(const uint2*)(featb + (size_t)s2 * 64 + l8 * 2);
            uint2 g3 = *(const uint2*)(featb + (size_t)s3 * 64 + l8 * 2);
            lo0 += bf2_unpack(g0.x); hi0 += bf2_unpack(g0.y);
            lo1 += bf2_unpack(g1.x); hi1 += bf2_unpack(g1.y);
            lo2 += bf2_unpack(g2.x); hi2 += bf2_unpack(g2.y);
            lo3 += bf2_unpack(g3.x); hi3 += bf2_unpack(g3.y);
            j += 8;
        }
        for (; j < m; j += 2){
            int jj = j + half;
            int s0 = __shfl(idx, jj < m ? jj : j, 64);
            uint2 g = *(const uint2*)(featb + (size_t)s0 * 64 + l8 * 2);
            if (jj < m){ lo0 += bf2_unpack(g.x); hi0 += bf2_unpack(g.y); }
        }
    }
    f2 lo = ((lo0 + lo1) + (lo2 + lo3)) + ((lo4 + lo5) + (lo6 + lo7));
    f2 hi = ((hi0 + hi1) + (hi2 + hi3)) + ((hi4 + hi5) + (hi6 + hi7));
    lo[0] += __shfl_xor(lo[0], 32, 64);
    lo[1] += __shfl_xor(lo[1], 32, 64);
    hi[0] += __shfl_xor(hi[0], 32, 64);
    hi[1] += __shfl_xor(hi[1], 32, 64);
    if (half == 0){
        int deg = e - b;
        float scl = 1.0f / (float)(deg > 1 ? deg : 1);
        uint2 o;
        o.x = pack_bf2(lo[0] * scl, lo[1] * scl);
        o.y = pack_bf2(hi[0] * scl, hi[1] * scl);
        *(uint2*)(aggb + (size_t)node * 64 + l8 * 2) = o;
    }
}

// ---------- weight prep: [Wl;Wr] fp32 -> bf16, MFMA-b_frag-swizzled ----------
// Bsw 16B entry index ((s*8 + ct)*64 + l) holds W[s*32 + (l>>4)*8 + j][ct*16 + (l&15)],
// j = 0..7, where W[k][c] = k<128 ? Wl[k][c] : Wr[k-128][c].  4096 threads total.
__global__ __launch_bounds__(256) void k_wprep(const float* __restrict__ Wl,
                                               const float* __restrict__ Wr,
                                               uint32_t* __restrict__ Bsw){
    int t = blockIdx.x * 256 + threadIdx.x;   // 0..4095
    int s = t >> 9, ct = (t >> 6) & 7, l = t & 63;
    int k0 = s * 32 + (l >> 4) * 8;
    int c  = ct * 16 + (l & 15);
    unsigned short e[8];
    #pragma unroll
    for (int j = 0; j < 8; ++j){
        int k = k0 + j;
        float v = (k < 128) ? Wl[(size_t)k * 128 + c] : Wr[(size_t)(k - 128) * 128 + c];
        e[j] = (unsigned short)f2bf(v);
    }
    uint32_t* o = Bsw + (size_t)t * 4;
    o[0] = (uint32_t)e[0] | ((uint32_t)e[1] << 16);
    o[1] = (uint32_t)e[2] | ((uint32_t)e[3] << 16);
    o[2] = (uint32_t)e[4] | ((uint32_t)e[5] << 16);
    o[3] = (uint32_t)e[6] | ((uint32_t)e[7] << 16);
}

// ---------- MFMA SAGE linear: out = relu([A1|A2] @ Bsw + bias) ----------
// LDS-free: a_frag = 16B contiguous load from the bf16 row; b_frag = coalesced
// 1KB/wave load from the pre-swizzled Bsw (L2-hot, 64KB). K=256 fully unrolled:
// 8 k-steps x (1 a-load + 8 b-loads + 8 MFMA). C/D mapping (m89-verified):
// col = lane&15, row = (lane>>4)*4 + reg. Rows are wave-private, so
// outbf may alias A2b (layer 1: xbf==hbf) — acc depends on all A2 loads,
// stores follow. OOB waves clamp loads to row M-1 and store nothing.
__global__ __launch_bounds__(256) void k_sage_mfma(
    const uint32_t* __restrict__ A1b, const uint32_t* __restrict__ A2b,
    const uint32_t* __restrict__ Bsw, const float* __restrict__ bias,
    float* __restrict__ outf, uint32_t* __restrict__ outbf, int M)
{
    int tid = threadIdx.x;
    int w = tid >> 6, l = tid & 63;
    int l15 = l & 15, l4 = l >> 4;
    int row = blockIdx.x * 64 + w * 16 + l15;
    int rowc = row < M ? row : M - 1;
    const char* a1p = (const char*)(A1b + (size_t)rowc * 64) + l4 * 16;
    const char* a2p = (const char*)(A2b + (size_t)rowc * 64) + l4 * 16;
    const char* bp  = (const char*)Bsw + (size_t)l * 16;

    f4 acc[8];
    #pragma unroll
    for (int ct = 0; ct < 8; ++ct) acc[ct] = f4_zero();

    #pragma unroll
    for (int s = 0; s < 8; ++s){
        bfv8 a = *(const bfv8*)((s < 4 ? a1p : a2p) + (s & 3) * 64);
        #pragma unroll
        for (int ct = 0; ct < 8; ++ct){
            bfv8 b = *(const bfv8*)(bp + (size_t)(s * 8 + ct) * 1024);
            acc[ct] = __builtin_amdgcn_mfma_f32_16x16x32_bf16(a, b, acc[ct], 0, 0, 0);
        }
    }

    int orow0 = blockIdx.x * 64 + w * 16 + l4 * 4;
    #pragma unroll
    for (int ct = 0; ct < 8; ++ct){
        int col = ct * 16 + l15;
        float bb = bias[col];
        #pragma unroll
        for (int r = 0; r < 4; ++r){
            int orow = orow0 + r;
            if (orow < M){
                float v = acc[ct][r] + bb;
                v = v > 0.f ? v : 0.f;
                if (outf)  outf[(size_t)orow * 128 + col] = v;
                if (outbf) ((unsigned short*)outbf)[(size_t)orow * 128 + col] =
                               (unsigned short)f2bf(v);
            }
        }
    }
}

extern "C" void kernel_launch(void* const* d_in, const int* in_sizes, int n_in,
                              void* d_out, int out_size, void* d_ws, size_t ws_size,
                              hipStream_t stream) {
    const float* x    = (const float*)d_in[0];
    const float* Wl1  = (const float*)d_in[1];
    const float* bl1  = (const float*)d_in[2];
    const float* Wr1  = (const float*)d_in[3];
    const float* Wl2  = (const float*)d_in[4];
    const float* bl2  = (const float*)d_in[5];
    const float* Wr2  = (const float*)d_in[6];
    const void*  eidx = d_in[7];
    float* out = (float*)d_out;

    const int N  = in_sizes[0] / 128;
    const int E  = in_sizes[7] / 2;
    const int NB = (N + 127) >> 7;          // 128-node coarse buckets (<=1024)

    char* ws = (char*)d_ws;
    size_t off = 0;
    auto alloc = [&](size_t bytes) -> void* {
        void* p = ws + off;
        off += (bytes + 255) & ~(size_t)255;
        return p;
    };
    int*      blkhist  = (int*)     alloc((size_t)NB * PB * 4);
    int*      coff     = (int*)     alloc((size_t)(NB + 1) * 4);
    int*      offs     = (int*)     alloc((size_t)NB * PB * 4);
    int*      esrc     = (int*)     alloc((size_t)E * 4);
    int*      rowptr   = (int*)     alloc((size_t)(N + 1) * 4);
    uint32_t* bsw1     = (uint32_t*)alloc(65536);
    uint32_t* bsw2     = (uint32_t*)alloc(65536);
    // unionA: bucketed (E*4, dead after bucketsort) then aggb (N*64*4)
    size_t uA = (size_t)E * 4 > (size_t)N * 256 ? (size_t)E * 4 : (size_t)N * 256;
    uint32_t* unionA   = (uint32_t*)alloc(uA);
    uint32_t* bucketed = unionA;
    uint32_t* aggb     = unionA;
    // unionB: xbf (dead after layer-1 gemm reads it) then hbf (written by gemm1)
    uint32_t* unionB   = (uint32_t*)alloc((size_t)N * 256);
    uint32_t* xbf      = unionB;
    uint32_t* hbf      = unionB;

    const int GB = (N + 63) / 64;           // gemm blocks

    // ---- bf16 feature table + swizzled weights + dst-sorted CSR ----
    k_tobf16    <<<(N * 32 + 255) / 256, 256, 0, stream>>>((const f4*)x, (uint2*)xbf, N * 32);
    k_wprep     <<<16, 256, 0, stream>>>(Wl1, Wr1, bsw1);
    k_wprep     <<<16, 256, 0, stream>>>(Wl2, Wr2, bsw2);
    k_hist      <<<PB, 1024, 0, stream>>>(eidx, E, NB, blkhist);
    k_offsets   <<<1, 1024, 0, stream>>>(blkhist, NB, coff, offs);
    k_scatter   <<<PB, 1024, 0, stream>>>(eidx, E, NB, offs, bucketed);
    k_bucketsort<<<NB, 1024, 0, stream>>>(bucketed, coff, esrc, rowptr, N, E, NB);

    // ---- layer 1: h = relu(mean_agg(x) @ Wl1 + bl1 + x @ Wr1) ----
    k_aggregate<<<(N + 3) / 4, 256, 0, stream>>>(xbf, rowptr, esrc, aggb, N);
    k_sage_mfma<<<GB, 256, 0, stream>>>(aggb, xbf, bsw1, bl1, nullptr, hbf, N);

    // ---- layer 2: out = relu(mean_agg(h) @ Wl2 + bl2 + h @ Wr2) ----
    k_aggregate<<<(N + 3) / 4, 256, 0, stream>>>(hbf, rowptr, esrc, aggb, N);
    k_sage_mfma<<<GB, 256, 0, stream>>>(aggb, hbf, bsw2, bl2, out, nullptr, N);
}

// Round 15
// 353.186 us; speedup vs baseline: 1.1970x; 1.1970x over previous
//
#include <hip/hip_runtime.h>
#include <cstdint>

typedef float f4 __attribute__((ext_vector_type(4)));
typedef float f2 __attribute__((ext_vector_type(2)));
typedef short bfv8 __attribute__((ext_vector_type(8)));   // 8 bf16 = 4 VGPR

__device__ inline f4 f4_zero(){ f4 v = {0.f,0.f,0.f,0.f}; return v; }
__device__ inline f2 f2_zero(){ f2 v = {0.f,0.f}; return v; }

// bf16 helpers: RNE pack, exact unpack
__device__ inline uint32_t f2bf(float f){
    uint32_t u = __float_as_uint(f);
    return (u + 0x7fffu + ((u >> 16) & 1u)) >> 16;
}
__device__ inline uint32_t pack_bf2(float a, float b){
    return f2bf(a) | (f2bf(b) << 16);
}
__device__ inline f2 bf2_unpack(uint32_t v){
    f2 r;
    r[0] = __uint_as_float(v << 16);
    r[1] = __uint_as_float(v & 0xffff0000u);
    return r;
}

#define PB 256  // blocks for hist/scatter. R12 lesson: PB IS the grid size for the
                // edge-stream kernels — PB=64 left 3/4 of CUs idle (−38us). Keep 256.
                // R14 lesson: do NOT fuse the offsets chain into one block — the
                // three NB-block kernels below are parallel across CUs; the fused
                // single-block version serialized 800KB on one CU (+80us).

// ---------- inline int64-vs-int32 detection ----------
// Checks high words of first 2048 index pairs; all zero => int64. Each block
// redundantly computes the same deterministic answer (16KB read, L2-hot).
__device__ inline bool detect_is64(const uint32_t* p, int* sflag){
    int t = threadIdx.x;
    if (t == 0) *sflag = 0;
    __syncthreads();
    int local = 0;
    for (int i = t; i < 2048; i += blockDim.x)
        if (p[2*i + 1] != 0u) local = 1;
    if (local) atomicOr(sflag, 1);
    __syncthreads();
    return *sflag == 0;
}

// ---------- fp32 -> packed bf16 conversion ----------
__global__ __launch_bounds__(256) void k_tobf16(const f4* __restrict__ in,
                                                uint2* __restrict__ out, int n4){
    int i = blockIdx.x * 256 + threadIdx.x;
    if (i >= n4) return;
    f4 v = in[i];
    uint2 o;
    o.x = pack_bf2(v[0], v[1]);
    o.y = pack_bf2(v[2], v[3]);
    out[i] = o;
}

// ---------- per-block coarse histogram (bucket = dst>>7) ----------
__global__ __launch_bounds__(1024) void k_hist(const void* __restrict__ eidx, int E, int NB,
                                               int* __restrict__ blkhist){
    __shared__ int lh[1024];
    __shared__ int dflag;
    bool is64 = detect_is64((const uint32_t*)eidx, &dflag);
    int t = threadIdx.x, blk = blockIdx.x;
    for (int i = t; i < NB; i += 1024) lh[i] = 0;
    __syncthreads();
    int R = (E + PB - 1) / PB;
    int s = blk * R, e_end = s + R < E ? s + R : E;
    const uint32_t* p32 = (const uint32_t*)eidx;
    const int*      pi  = (const int*)eidx;
    for (int e = s + t; e < e_end; e += 1024){
        int d = is64 ? (int)p32[2*(size_t)(E + e)] : pi[(size_t)E + e];
        atomicAdd(&lh[d >> 7], 1);
    }
    __syncthreads();
    for (int i = t; i < NB; i += 1024)
        blkhist[(size_t)i * PB + blk] = lh[i];      // block-private slot, no atomic
}

// ---------- per-bucket totals (parallel: NB blocks) ----------
__global__ __launch_bounds__(PB) void k_btot(const int* __restrict__ blkhist,
                                             int* __restrict__ tot){
    int b = blockIdx.x, t = threadIdx.x, lane = t & 63, w = t >> 6;
    int v = blkhist[(size_t)b * PB + t];
    #pragma unroll
    for (int off = 32; off; off >>= 1) v += __shfl_down(v, off, 64);
    __shared__ int ws[4];
    if (lane == 0) ws[w] = v;
    __syncthreads();
    if (t == 0) tot[b] = ws[0] + ws[1] + ws[2] + ws[3];
}

// ---------- exclusive scan of bucket totals (1 block; NB <= 1024 ints only) ----------
__global__ __launch_bounds__(1024) void k_bscan(const int* __restrict__ tot, int n,
                                                int* __restrict__ coff){
    int t = threadIdx.x, lane = t & 63, w = t >> 6;
    int v = (t < n) ? tot[t] : 0;
    int x = v;
    #pragma unroll
    for (int off = 1; off < 64; off <<= 1){
        int u = __shfl_up(x, off, 64);
        if (lane >= off) x += u;
    }
    __shared__ int ws[16];
    if (lane == 63) ws[w] = x;
    __syncthreads();
    if (w == 0 && lane < 16){
        int y = ws[lane];
        #pragma unroll
        for (int off = 1; off < 16; off <<= 1){
            int u = __shfl_up(y, off, 64);
            if (lane >= off) y += u;
        }
        ws[lane] = y;
    }
    __syncthreads();
    int incl = x + (w ? ws[w - 1] : 0);
    if (t < n)     coff[t] = incl - v;
    if (t == n - 1) coff[n] = incl;     // == E
}

// ---------- per-(bucket,block) offsets (parallel: NB blocks) ----------
__global__ __launch_bounds__(PB) void k_boff(const int* __restrict__ blkhist,
                                             const int* __restrict__ coff,
                                             int* __restrict__ offs){
    int b = blockIdx.x, t = threadIdx.x, lane = t & 63, w = t >> 6;
    int h = blkhist[(size_t)b * PB + t];
    int x = h;
    #pragma unroll
    for (int off = 1; off < 64; off <<= 1){
        int u = __shfl_up(x, off, 64);
        if (lane >= off) x += u;
    }
    __shared__ int ws[4];
    if (lane == 63) ws[w] = x;
    __syncthreads();
    int add = 0;
    for (int j = 0; j < w; ++j) add += ws[j];
    offs[(size_t)b * PB + t] = coff[b] + add + x - h;   // exclusive within bucket
}

// ---------- scatter edges into coarse buckets (packed (dst&127)<<17 | src) ----------
__global__ __launch_bounds__(1024) void k_scatter(const void* __restrict__ eidx, int E, int NB,
                                                  const int* __restrict__ offs,
                                                  uint32_t* __restrict__ bucketed){
    __shared__ int cur[1024];
    __shared__ int dflag;
    bool is64 = detect_is64((const uint32_t*)eidx, &dflag);
    int t = threadIdx.x, blk = blockIdx.x;
    for (int i = t; i < NB; i += 1024) cur[i] = offs[(size_t)i * PB + blk];
    __syncthreads();
    int R = (E + PB - 1) / PB;
    int s = blk * R, e_end = s + R < E ? s + R : E;
    const uint32_t* p32 = (const uint32_t*)eidx;
    const int*      pi  = (const int*)eidx;
    for (int e = s + t; e < e_end; e += 1024){
        int sv, dv;
        if (is64){ sv = (int)p32[2*(size_t)e]; dv = (int)p32[2*(size_t)(E + e)]; }
        else     { sv = pi[e];                 dv = pi[(size_t)E + e]; }
        int b = dv >> 7;
        int pos = atomicAdd(&cur[b], 1);      // LDS atomic; global range block-private
        bucketed[pos] = ((uint32_t)(dv & 127) << 17) | (uint32_t)sv;
    }
}

// ---------- per-bucket counting sort -> full dst-sorted CSR ----------
__global__ __launch_bounds__(1024) void k_bucketsort(const uint32_t* __restrict__ bucketed,
                                                     const int* __restrict__ coff,
                                                     int* __restrict__ esrc,
                                                     int* __restrict__ rowptr,
                                                     int N, int E, int NB){
    __shared__ int hist[128], cur[128], wtot[2];
    int b = blockIdx.x, t = threadIdx.x;
    if (t < 128) hist[t] = 0;
    __syncthreads();
    int s = coff[b], e_end = coff[b + 1];
    for (int i = s + t; i < e_end; i += 1024)
        atomicAdd(&hist[bucketed[i] >> 17], 1);
    __syncthreads();
    int x = 0, v = 0;
    if (t < 128){
        int lane = t & 63;
        v = hist[t]; x = v;
        #pragma unroll
        for (int off = 1; off < 64; off <<= 1){
            int u = __shfl_up(x, off, 64);
            if (lane >= off) x += u;
        }
        if (lane == 63) wtot[t >> 6] = x;
    }
    __syncthreads();
    if (t < 128){
        int w = t >> 6;
        int excl = x - v + (w ? wtot[0] : 0);     // exclusive within bucket
        int abs0 = s + excl;
        cur[t] = abs0;
        int node = b * 128 + t;
        if (node < N) rowptr[node] = abs0;
    }
    if (b == NB - 1 && t == 0) rowptr[N] = E;
    __syncthreads();
    for (int i = s + t; i < e_end; i += 1024){
        uint32_t val = bucketed[i];
        int r = (int)(val >> 17);
        int pos = atomicAdd(&cur[r], 1);
        esrc[pos] = (int)(val & 0x1FFFFu);
    }
}

// ---------- mean aggregation over bf16 features: one wave per dst node ----------
// 2 edges per step: lanes 0-31 even edge, 32-63 odd edge; each lane gathers 8B
// (4 bf16) via dwordx2. Cascade unroll 16/8/2 so mean-deg-16 rows hit the wide
// path: up to 8 dwordx2 loads in flight per half-wave (16/wave). Cross-half
// shfl_xor(32) reduce; lanes 0-31 store 8B.
__global__ __launch_bounds__(256) void k_aggregate(const uint32_t* __restrict__ featb,
                                                   const int* __restrict__ rowptr,
                                                   const int* __restrict__ esrc,
                                                   uint32_t* __restrict__ aggb, int N){
    int node = blockIdx.x * 4 + (threadIdx.x >> 6);
    if (node >= N) return;
    int lane = threadIdx.x & 63;
    int half = lane >> 5;          // which edge of the pair
    int l8   = lane & 31;          // 8-byte chunk within row
    int b = rowptr[node], e = rowptr[node + 1];
    f2 lo0=f2_zero(),lo1=f2_zero(),lo2=f2_zero(),lo3=f2_zero();
    f2 lo4=f2_zero(),lo5=f2_zero(),lo6=f2_zero(),lo7=f2_zero();
    f2 hi0=f2_zero(),hi1=f2_zero(),hi2=f2_zero(),hi3=f2_zero();
    f2 hi4=f2_zero(),hi5=f2_zero(),hi6=f2_zero(),hi7=f2_zero();
    for (int base = b; base < e; base += 64){
        int m = e - base; if (m > 64) m = 64;
        int idx = (lane < m) ? esrc[base + lane] : 0;   // vector load, 256B/wave
        int j = 0;
        for (; j + 16 <= m; j += 16){
            int s0 = __shfl(idx, j      + half, 64);
            int s1 = __shfl(idx, j + 2  + half, 64);
            int s2 = __shfl(idx, j + 4  + half, 64);
            int s3 = __shfl(idx, j + 6  + half, 64);
            int s4 = __shfl(idx, j + 8  + half, 64);
            int s5 = __shfl(idx, j + 10 + half, 64);
            int s6 = __shfl(idx, j + 12 + half, 64);
            int s7 = __shfl(idx, j + 14 + half, 64);
            uint2 g0 = *(const uint2*)(featb + (size_t)s0 * 64 + l8 * 2);
            uint2 g1 = *(const uint2*)(featb + (size_t)s1 * 64 + l8 * 2);
            uint2 g2 = *(const uint2*)(featb + (size_t)s2 * 64 + l8 * 2);
            uint2 g3 = *(const uint2*)(featb + (size_t)s3 * 64 + l8 * 2);
            uint2 g4 = *(const uint2*)(featb + (size_t)s4 * 64 + l8 * 2);
            uint2 g5 = *(const uint2*)(featb + (size_t)s5 * 64 + l8 * 2);
            uint2 g6 = *(const uint2*)(featb + (size_t)s6 * 64 + l8 * 2);
            uint2 g7 = *(const uint2*)(featb + (size_t)s7 * 64 + l8 * 2);
            lo0 += bf2_unpack(g0.x); hi0 += bf2_unpack(g0.y);
            lo1 += bf2_unpack(g1.x); hi1 += bf2_unpack(g1.y);
            lo2 += bf2_unpack(g2.x); hi2 += bf2_unpack(g2.y);
            lo3 += bf2_unpack(g3.x); hi3 += bf2_unpack(g3.y);
            lo4 += bf2_unpack(g4.x); hi4 += bf2_unpack(g4.y);
            lo5 += bf2_unpack(g5.x); hi5 += bf2_unpack(g5.y);
            lo6 += bf2_unpack(g6.x); hi6 += bf2_unpack(g6.y);
            lo7 += bf2_unpack(g7.x); hi7 += bf2_unpack(g7.y);
        }
        if (j + 8 <= m){
            int s0 = __shfl(idx, j     + half, 64);
            int s1 = __shfl(idx, j + 2 + half, 64);
            int s2 = __shfl(idx, j + 4 + half, 64);
            int s3 = __shfl(idx, j + 6 + half, 64);
            uint2 g0 = *(const uint2*)(featb + (size_t)s0 * 64 + l8 * 2);
            uint2 g1 = *(const uint2*)(featb + (size_t)s1 * 64 + l8 * 2);
            uint2 g2 = *(const uint2*)(featb + (size_t)s2 * 64 + l8 * 2);
            uint2 g3 = *(const uint2*)(featb + (size_t)s3 * 64 + l8 * 2);
            lo0 += bf2_unpack(g0.x); hi0 += bf2_unpack(g0.y);
            lo1 += bf2_unpack(g1.x); hi1 += bf2_unpack(g1.y);
            lo2 += bf2_unpack(g2.x); hi2 += bf2_unpack(g2.y);
            lo3 += bf2_unpack(g3.x); hi3 += bf2_unpack(g3.y);
            j += 8;
        }
        for (; j < m; j += 2){
            int jj = j + half;
            int s0 = __shfl(idx, jj < m ? jj : j, 64);
            uint2 g = *(const uint2*)(featb + (size_t)s0 * 64 + l8 * 2);
            if (jj < m){ lo0 += bf2_unpack(g.x); hi0 += bf2_unpack(g.y); }
        }
    }
    f2 lo = ((lo0 + lo1) + (lo2 + lo3)) + ((lo4 + lo5) + (lo6 + lo7));
    f2 hi = ((hi0 + hi1) + (hi2 + hi3)) + ((hi4 + hi5) + (hi6 + hi7));
    lo[0] += __shfl_xor(lo[0], 32, 64);
    lo[1] += __shfl_xor(lo[1], 32, 64);
    hi[0] += __shfl_xor(hi[0], 32, 64);
    hi[1] += __shfl_xor(hi[1], 32, 64);
    if (half == 0){
        int deg = e - b;
        float scl = 1.0f / (float)(deg > 1 ? deg : 1);
        uint2 o;
        o.x = pack_bf2(lo[0] * scl, lo[1] * scl);
        o.y = pack_bf2(hi[0] * scl, hi[1] * scl);
        *(uint2*)(aggb + (size_t)node * 64 + l8 * 2) = o;
    }
}

// ---------- weight prep: [Wl;Wr] fp32 -> bf16, MFMA-b_frag-swizzled ----------
// Bsw 16B entry index ((s*8 + ct)*64 + l) holds W[s*32 + (l>>4)*8 + j][ct*16 + (l&15)],
// j = 0..7, where W[k][c] = k<128 ? Wl[k][c] : Wr[k-128][c].  4096 threads total.
__global__ __launch_bounds__(256) void k_wprep(const float* __restrict__ Wl,
                                               const float* __restrict__ Wr,
                                               uint32_t* __restrict__ Bsw){
    int t = blockIdx.x * 256 + threadIdx.x;   // 0..4095
    int s = t >> 9, ct = (t >> 6) & 7, l = t & 63;
    int k0 = s * 32 + (l >> 4) * 8;
    int c  = ct * 16 + (l & 15);
    unsigned short e[8];
    #pragma unroll
    for (int j = 0; j < 8; ++j){
        int k = k0 + j;
        float v = (k < 128) ? Wl[(size_t)k * 128 + c] : Wr[(size_t)(k - 128) * 128 + c];
        e[j] = (unsigned short)f2bf(v);
    }
    uint32_t* o = Bsw + (size_t)t * 4;
    o[0] = (uint32_t)e[0] | ((uint32_t)e[1] << 16);
    o[1] = (uint32_t)e[2] | ((uint32_t)e[3] << 16);
    o[2] = (uint32_t)e[4] | ((uint32_t)e[5] << 16);
    o[3] = (uint32_t)e[6] | ((uint32_t)e[7] << 16);
}

// ---------- MFMA SAGE linear: out = relu([A1|A2] @ Bsw + bias) ----------
// LDS-free: a_frag = 16B contiguous load from the bf16 row; b_frag = coalesced
// 1KB/wave load from the pre-swizzled Bsw (L2-hot, 64KB). K=256 fully unrolled:
// 8 k-steps x (1 a-load + 8 b-loads + 8 MFMA). C/D mapping (m89-verified):
// col = lane&15, row = (lane>>4)*4 + reg. Rows are wave-private, so
// outbf may alias A2b (layer 1: xbf==hbf) — acc depends on all A2 loads,
// stores follow. OOB waves clamp loads to row M-1 and store nothing.
__global__ __launch_bounds__(256) void k_sage_mfma(
    const uint32_t* __restrict__ A1b, const uint32_t* __restrict__ A2b,
    const uint32_t* __restrict__ Bsw, const float* __restrict__ bias,
    float* __restrict__ outf, uint32_t* __restrict__ outbf, int M)
{
    int tid = threadIdx.x;
    int w = tid >> 6, l = tid & 63;
    int l15 = l & 15, l4 = l >> 4;
    int row = blockIdx.x * 64 + w * 16 + l15;
    int rowc = row < M ? row : M - 1;
    const char* a1p = (const char*)(A1b + (size_t)rowc * 64) + l4 * 16;
    const char* a2p = (const char*)(A2b + (size_t)rowc * 64) + l4 * 16;
    const char* bp  = (const char*)Bsw + (size_t)l * 16;

    f4 acc[8];
    #pragma unroll
    for (int ct = 0; ct < 8; ++ct) acc[ct] = f4_zero();

    #pragma unroll
    for (int s = 0; s < 8; ++s){
        bfv8 a = *(const bfv8*)((s < 4 ? a1p : a2p) + (s & 3) * 64);
        #pragma unroll
        for (int ct = 0; ct < 8; ++ct){
            bfv8 b = *(const bfv8*)(bp + (size_t)(s * 8 + ct) * 1024);
            acc[ct] = __builtin_amdgcn_mfma_f32_16x16x32_bf16(a, b, acc[ct], 0, 0, 0);
        }
    }

    int orow0 = blockIdx.x * 64 + w * 16 + l4 * 4;
    #pragma unroll
    for (int ct = 0; ct < 8; ++ct){
        int col = ct * 16 + l15;
        float bb = bias[col];
        #pragma unroll
        for (int r = 0; r < 4; ++r){
            int orow = orow0 + r;
            if (orow < M){
                float v = acc[ct][r] + bb;
                v = v > 0.f ? v : 0.f;
                if (outf)  outf[(size_t)orow * 128 + col] = v;
                if (outbf) ((unsigned short*)outbf)[(size_t)orow * 128 + col] =
                               (unsigned short)f2bf(v);
            }
        }
    }
}

extern "C" void kernel_launch(void* const* d_in, const int* in_sizes, int n_in,
                              void* d_out, int out_size, void* d_ws, size_t ws_size,
                              hipStream_t stream) {
    const float* x    = (const float*)d_in[0];
    const float* Wl1  = (const float*)d_in[1];
    const float* bl1  = (const float*)d_in[2];
    const float* Wr1  = (const float*)d_in[3];
    const float* Wl2  = (const float*)d_in[4];
    const float* bl2  = (const float*)d_in[5];
    const float* Wr2  = (const float*)d_in[6];
    const void*  eidx = d_in[7];
    float* out = (float*)d_out;

    const int N  = in_sizes[0] / 128;
    const int E  = in_sizes[7] / 2;
    const int NB = (N + 127) >> 7;          // 128-node coarse buckets (<=1024)

    char* ws = (char*)d_ws;
    size_t off = 0;
    auto alloc = [&](size_t bytes) -> void* {
        void* p = ws + off;
        off += (bytes + 255) & ~(size_t)255;
        return p;
    };
    int*      blkhist  = (int*)     alloc((size_t)NB * PB * 4);
    int*      tot      = (int*)     alloc((size_t)NB * 4);
    int*      coff     = (int*)     alloc((size_t)(NB + 1) * 4);
    int*      offs     = (int*)     alloc((size_t)NB * PB * 4);
    int*      esrc     = (int*)     alloc((size_t)E * 4);
    int*      rowptr   = (int*)     alloc((size_t)(N + 1) * 4);
    uint32_t* bsw1     = (uint32_t*)alloc(65536);
    uint32_t* bsw2     = (uint32_t*)alloc(65536);
    // unionA: bucketed (E*4, dead after bucketsort) then aggb (N*64*4)
    size_t uA = (size_t)E * 4 > (size_t)N * 256 ? (size_t)E * 4 : (size_t)N * 256;
    uint32_t* unionA   = (uint32_t*)alloc(uA);
    uint32_t* bucketed = unionA;
    uint32_t* aggb     = unionA;
    // unionB: xbf (dead after layer-1 gemm reads it) then hbf (written by gemm1)
    uint32_t* unionB   = (uint32_t*)alloc((size_t)N * 256);
    uint32_t* xbf      = unionB;
    uint32_t* hbf      = unionB;

    const int GB = (N + 63) / 64;           // gemm blocks

    // ---- bf16 feature table + swizzled weights + dst-sorted CSR ----
    k_tobf16    <<<(N * 32 + 255) / 256, 256, 0, stream>>>((const f4*)x, (uint2*)xbf, N * 32);
    k_wprep     <<<16, 256, 0, stream>>>(Wl1, Wr1, bsw1);
    k_wprep     <<<16, 256, 0, stream>>>(Wl2, Wr2, bsw2);
    k_hist      <<<PB, 1024, 0, stream>>>(eidx, E, NB, blkhist);
    k_btot      <<<NB, PB,   0, stream>>>(blkhist, tot);
    k_bscan     <<<1, 1024,  0, stream>>>(tot, NB, coff);
    k_boff      <<<NB, PB,   0, stream>>>(blkhist, coff, offs);
    k_scatter   <<<PB, 1024, 0, stream>>>(eidx, E, NB, offs, bucketed);
    k_bucketsort<<<NB, 1024, 0, stream>>>(bucketed, coff, esrc, rowptr, N, E, NB);

    // ---- layer 1: h = relu(mean_agg(x) @ Wl1 + bl1 + x @ Wr1) ----
    k_aggregate<<<(N + 3) / 4, 256, 0, stream>>>(xbf, rowptr, esrc, aggb, N);
    k_sage_mfma<<<GB, 256, 0, stream>>>(aggb, xbf, bsw1, bl1, nullptr, hbf, N);

    // ---- layer 2: out = relu(mean_agg(h) @ Wl2 + bl2 + h @ Wr2) ----
    k_aggregate<<<(N + 3) / 4, 256, 0, stream>>>(hbf, rowptr, esrc, aggb, N);
    k_sage_mfma<<<GB, 256, 0, stream>>>(aggb, hbf, bsw2, bl2, out, nullptr, N);
}